// Round 19
// baseline (93.084 us; speedup 1.0000x reference)
//
#include <hip/hip_runtime.h>
#include <hip/hip_bf16.h>

#define DIM 32
#define LOG_NPB 7
#define NPB 128              // nodes per bucket
#define NBINS 800            // >= ceil(100000/128)=782
#define NBINS_PAD 1024
#define EPB 6144             // edges per scatter block (24 KB LDS stage)
#define EPT 12               // edges per thread (EPB/512)
#define MAXSEG 384           // max descriptors per bucket (<= 261 in practice)
#define ENTCAP 4096          // per-bucket LDS staging capacity

// ---------------------------------------------------------------------------
// Kernel 1: out = x @ W2^T + b2 (fp32) ;  y = x @ W1^T (bf16 packed).
// Weights in registers per lane (r17 shape).
// ---------------------------------------------------------------------------
__global__ __launch_bounds__(256) void fused_lin_kernel(
    const float* __restrict__ x,
    const float* __restrict__ W1,
    const float* __restrict__ W2,
    const float* __restrict__ b2,
    float* __restrict__ out,
    unsigned* __restrict__ y32,
    int n_nodes)
{
    __shared__ float xs[8][DIM];

    const int t = threadIdx.x;
    const int r = t >> 5;
    const int c = t & 31;

    float4 w1r[8], w2r[8];
    #pragma unroll
    for (int q = 0; q < 8; ++q) {
        w1r[q] = *(const float4*)(W1 + c * DIM + q * 4);
        w2r[q] = *(const float4*)(W2 + c * DIM + q * 4);
    }
    const float bias = b2[c];

    const int ntiles = (n_nodes + 7) >> 3;

    for (int tile = blockIdx.x; tile < ntiles; tile += gridDim.x) {
        const int row = tile * 8 + r;
        __syncthreads();
        if (row < n_nodes) xs[r][c] = x[(long)row * DIM + c];
        __syncthreads();
        if (row < n_nodes) {
            const float4* xr = (const float4*)xs[r];
            float a2 = bias;
            float a1 = 0.0f;
            #pragma unroll
            for (int q = 0; q < 8; ++q) {
                float4 xv = xr[q];
                a2 += xv.x * w2r[q].x + xv.y * w2r[q].y + xv.z * w2r[q].z + xv.w * w2r[q].w;
                a1 += xv.x * w1r[q].x + xv.y * w1r[q].y + xv.z * w1r[q].z + xv.w * w1r[q].w;
            }
            out[(long)row * DIM + c] = a2;
            float hi = __shfl_down(a1, 1);
            if ((c & 1) == 0) {
                __hip_bfloat16 blo = __float2bfloat16(a1);
                __hip_bfloat16 bhi = __float2bfloat16(hi);
                unsigned pack = ((unsigned)(*(unsigned short*)&bhi) << 16)
                              | (unsigned)(*(unsigned short*)&blo);
                y32[(size_t)row * 16 + (c >> 1)] = pack;
            }
        }
    }
}

// ---------------------------------------------------------------------------
// Pass 1: BLOCK-PRIVATE scatter. Each block bin-sorts its EPB edges in LDS
// and streams them to its own contiguous blkedges slice (no line sharing
// across XCDs), then appends (start<<8|cnt) descriptors per non-empty bin.
// ---------------------------------------------------------------------------
__global__ __launch_bounds__(512) void scatter_private_kernel(
    const int* __restrict__ src, const int* __restrict__ dst,
    unsigned* __restrict__ blkedges, unsigned* __restrict__ desc,
    int* __restrict__ nseg, int nE)
{
    __shared__ unsigned stage[EPB];        // 24 KB
    __shared__ int cnt[NBINS_PAD];         // 4 KB
    __shared__ int ex[NBINS_PAD];          // 4 KB
    __shared__ int wsum[8];

    const int t = threadIdx.x;
    const long base = (long)blockIdx.x * EPB;

    for (int i = t; i < NBINS_PAD; i += 512) cnt[i] = 0;
    __syncthreads();

    int bn[EPT], rk[EPT];
    unsigned pk[EPT];
    #pragma unroll
    for (int i = 0; i < EPT; ++i) {
        long e = base + (long)i * 512 + t;
        if (e < nE) {
            int s  = src[e];
            int dd = dst[e];
            bn[i] = dd >> LOG_NPB;
            pk[i] = ((unsigned)s << LOG_NPB) | (unsigned)(dd & (NPB - 1));
            rk[i] = atomicAdd(&cnt[bn[i]], 1);
        } else bn[i] = -1;
    }
    __syncthreads();

    // exclusive scan over 1024 bins: 2 bins/thread + wave scan + wave offsets
    {
        int c0 = cnt[2 * t];
        int c1 = cnt[2 * t + 1];
        int v  = c0 + c1;
        const int lane = t & 63, wv = t >> 6;
        #pragma unroll
        for (int off = 1; off < 64; off <<= 1) {
            int u = __shfl_up(v, off);
            if (lane >= off) v += u;
        }
        if (lane == 63) wsum[wv] = v;
        __syncthreads();
        int woff = 0;
        for (int w = 0; w < wv; ++w) woff += wsum[w];
        int pbase = woff + v - (c0 + c1);
        ex[2 * t]     = pbase;
        ex[2 * t + 1] = pbase + c0;
    }
    __syncthreads();

    // stage in bin-sorted order
    #pragma unroll
    for (int i = 0; i < EPT; ++i)
        if (bn[i] >= 0) stage[ex[bn[i]] + rk[i]] = pk[i];
    __syncthreads();

    // stream out to the block-private slice (fully coalesced, lines owned once)
    const int n_this = (int)((nE - base < (long)EPB) ? (nE - base) : EPB);
    for (int i = t; i < n_this; i += 512)
        blkedges[base + i] = stage[i];

    // publish descriptors: (global_start << 8) | cnt   (cnt<=255 per chunk)
    for (int b = t; b < NBINS; b += 512) {
        int c = cnt[b];
        int gs = (int)base + ex[b];
        while (c > 0) {
            int cc = (c > 255) ? 255 : c;
            int k = atomicAdd(&nseg[b], 1);
            if (k < MAXSEG) desc[b * MAXSEG + k] = ((unsigned)gs << 8) | (unsigned)cc;
            gs += cc; c -= cc;
        }
    }
}

// ---------------------------------------------------------------------------
// Pass 2: per-bucket segment assembly + LDS node-sort + pipelined gather.
// Load phase walks the bucket's descriptor list (contiguous) and copies
// segments with 16-lane groups, folding the node histogram into the copy.
// Sort + gather phases unchanged from the round-17/18 best.
// ---------------------------------------------------------------------------
__global__ __launch_bounds__(512) void sort_gather_kernel(
    const int* __restrict__ nseg, const unsigned* __restrict__ desc,
    const unsigned* __restrict__ blkedges,
    const unsigned short* __restrict__ yb,
    float* __restrict__ out, int n_nodes)
{
    __shared__ unsigned ent[ENTCAP];      // 16 KB
    __shared__ unsigned sorted[ENTCAP];   // 16 KB
    __shared__ int cnt[NPB];
    __shared__ int ex[NPB];
    __shared__ int cur[NPB];
    __shared__ int segoff[MAXSEG];
    __shared__ int tot;

    const int b = blockIdx.x;
    const int t = threadIdx.x;

    if (t == 0) tot = 0;
    if (t < NPB) { cnt[t] = 0; cur[t] = 0; }
    __syncthreads();

    int ns = nseg[b];
    if (ns > MAXSEG) ns = MAXSEG;

    // assign output offsets per segment (order-free)
    for (int si = t; si < ns; si += 512) {
        int c = (int)(desc[b * MAXSEG + si] & 255u);
        segoff[si] = atomicAdd(&tot, c);
    }
    __syncthreads();
    int n = tot;
    if (n > ENTCAP) n = ENTCAP;

    // copy segments: 16-lane group per segment, histogram folded in
    {
        const int g   = t >> 4;   // 0..31
        const int l16 = t & 15;
        for (int si = g; si < ns; si += 32) {
            unsigned dc = desc[b * MAXSEG + si];
            int c  = (int)(dc & 255u);
            int gs = (int)(dc >> 8);
            int o  = segoff[si];
            for (int j = l16; j < c; j += 16) {
                int oo = o + j;
                if (oo < ENTCAP) {
                    unsigned e = blkedges[gs + j];
                    ent[oo] = e;
                    atomicAdd(&cnt[e & (NPB - 1)], 1);
                }
            }
        }
    }
    __syncthreads();

    // single-wave exclusive scan over 128 bins (2 bins/lane)
    if (t < 64) {
        int c0 = cnt[2 * t];
        int c1 = cnt[2 * t + 1];
        int v  = c0 + c1;
        #pragma unroll
        for (int off = 1; off < 64; off <<= 1) {
            int u = __shfl_up(v, off);
            if (t >= off) v += u;
        }
        int pbase = v - (c0 + c1);
        ex[2 * t]     = pbase;
        ex[2 * t + 1] = pbase + c0;
    }
    __syncthreads();

    for (int i = t; i < n; i += 512) {
        unsigned e = ent[i];
        int bin = (int)(e & (NPB - 1));
        int r = atomicAdd(&cur[bin], 1);
        sorted[ex[bin] + r] = e >> LOG_NPB;
    }
    __syncthreads();

    // ---- pipelined gather phase (unchanged) ----
    const int wv   = t >> 6;
    const int lane = t & 63;
    const int slot = lane >> 3;
    const int li   = lane & 7;

    int ln   = wv;
    int node = b * NPB + ln;
    if (node >= n_nodes) return;

    int st = ex[ln];
    int d  = cnt[ln];
    int s[4];
    #pragma unroll
    for (int k = 0; k < 4; ++k) {
        int e = slot + 8 * k;
        int idx = (e < d) ? e : (d > 0 ? d - 1 : 0);
        s[k] = (int)sorted[(d > 0 ? st : 0) + idx];
    }
    float4 o = make_float4(0.f, 0.f, 0.f, 0.f);
    if (slot == 0) o = ((const float4*)(out + ((size_t)node << 5)))[li];

    while (true) {
        ushort4 u[4];
        #pragma unroll
        for (int k = 0; k < 4; ++k) {
            if (8 * k < d)
                u[k] = *(const ushort4*)(yb + ((size_t)s[k] << 5) + (li << 2));
        }

        const int ln_n   = ln + 8;
        const int node_n = node + 8;
        const bool have_n = (ln_n < NPB) && (node_n < n_nodes);
        int st_n = 0, d_n = 0;
        int sn[4];
        float4 o_n = make_float4(0.f, 0.f, 0.f, 0.f);
        if (have_n) {
            st_n = ex[ln_n];
            d_n  = cnt[ln_n];
            #pragma unroll
            for (int k = 0; k < 4; ++k) {
                int e = slot + 8 * k;
                int idx = (e < d_n) ? e : (d_n > 0 ? d_n - 1 : 0);
                sn[k] = (int)sorted[(d_n > 0 ? st_n : 0) + idx];
            }
            if (slot == 0) o_n = ((const float4*)(out + ((size_t)node_n << 5)))[li];
        }

        float a0 = 0.f, a1 = 0.f, a2 = 0.f, a3 = 0.f;
        #pragma unroll
        for (int k = 0; k < 4; ++k) {
            if (8 * k < d) {
                const bool v = (slot + 8 * k) < d;
                a0 += v ? __uint_as_float((unsigned)u[k].x << 16) : 0.f;
                a1 += v ? __uint_as_float((unsigned)u[k].y << 16) : 0.f;
                a2 += v ? __uint_as_float((unsigned)u[k].z << 16) : 0.f;
                a3 += v ? __uint_as_float((unsigned)u[k].w << 16) : 0.f;
            }
        }
        for (int e0 = 32 + slot; e0 < d; e0 += 8) {
            int ss = (int)sorted[st + e0];
            ushort4 uu = *(const ushort4*)(yb + ((size_t)ss << 5) + (li << 2));
            a0 += __uint_as_float((unsigned)uu.x << 16);
            a1 += __uint_as_float((unsigned)uu.y << 16);
            a2 += __uint_as_float((unsigned)uu.z << 16);
            a3 += __uint_as_float((unsigned)uu.w << 16);
        }

        #pragma unroll
        for (int m = 8; m < 64; m <<= 1) {
            a0 += __shfl_xor(a0, m);
            a1 += __shfl_xor(a1, m);
            a2 += __shfl_xor(a2, m);
            a3 += __shfl_xor(a3, m);
        }

        if (slot == 0 && d > 0) {
            float4 w;
            w.x = o.x + a0; w.y = o.y + a1; w.z = o.z + a2; w.w = o.w + a3;
            ((float4*)(out + ((size_t)node << 5)))[li] = w;
        }

        if (!have_n) break;
        ln = ln_n; node = node_n; st = st_n; d = d_n;
        s[0] = sn[0]; s[1] = sn[1]; s[2] = sn[2]; s[3] = sn[3];
        o = o_n;
    }
}

extern "C" void kernel_launch(void* const* d_in, const int* in_sizes, int n_in,
                              void* d_out, int out_size, void* d_ws, size_t ws_size,
                              hipStream_t stream) {
    const float* x  = (const float*)d_in[0];
    const float* W1 = (const float*)d_in[1];
    const float* W2 = (const float*)d_in[2];
    const float* b2 = (const float*)d_in[3];
    const int*   ei = (const int*)d_in[4];

    const int n_nodes = in_sizes[0] / DIM;   // 100000
    const int n_edges = in_sizes[4] / 2;     // 1,600,000
    const int* src = ei;
    const int* dst = ei + n_edges;
    float* out = (float*)d_out;

    const int nb = (n_nodes + NPB - 1) / NPB;    // 782

    char* basep = (char*)d_ws;
    size_t off = 0;
    auto alloc = [&](size_t bytes) {
        char* p = basep + off;
        off = (off + bytes + 255) & ~(size_t)255;
        return p;
    };
    unsigned* y32      = (unsigned*)alloc((size_t)n_nodes * DIM * sizeof(unsigned short));
    unsigned* blkedges = (unsigned*)alloc((size_t)n_edges * sizeof(unsigned));
    unsigned* desc     = (unsigned*)alloc((size_t)nb * MAXSEG * sizeof(unsigned));
    int*      nseg     = (int*)     alloc((size_t)nb * sizeof(int));
    (void)ws_size;

    hipMemsetAsync(nseg, 0, (size_t)nb * sizeof(int), stream);

    fused_lin_kernel<<<1024, 256, 0, stream>>>(x, W1, W2, b2, out, y32, n_nodes);
    scatter_private_kernel<<<(n_edges + EPB - 1) / EPB, 512, 0, stream>>>(
        src, dst, blkedges, desc, nseg, n_edges);
    sort_gather_kernel<<<nb, 512, 0, stream>>>(nseg, desc, blkedges,
                                               (const unsigned short*)y32, out, n_nodes);
}

// Round 20
// 78.205 us; speedup vs baseline: 1.1903x; 1.1903x over previous
//
#include <hip/hip_runtime.h>
#include <hip/hip_bf16.h>

#define DIM 32
#define LOG_NPB 7
#define NPB 128              // nodes per bucket
#define CAP 4096             // edge capacity per bucket (avg ~2046)
#define NBINS 800            // >= ceil(100000/128)=782
#define EPB 16384            // edges per scatter block
#define EPT 16               // edges per thread in scatter (EPB/1024)

// ---------------------------------------------------------------------------
// Kernel 1: y = x @ W1^T (bf16 packed) ONLY. W1 row held in registers.
// Block 0 also inits bucket cursors (absolute: cursor[b] = b*CAP).
// ---------------------------------------------------------------------------
__global__ __launch_bounds__(256) void lin_y_kernel(
    const float* __restrict__ x,
    const float* __restrict__ W1,
    unsigned* __restrict__ y32,
    int* __restrict__ cursor, int nb,
    int n_nodes)
{
    __shared__ float xs[8][DIM];

    const int t = threadIdx.x;
    if (blockIdx.x == 0) {
        for (int i = t; i < nb; i += 256) cursor[i] = i * CAP;
    }

    const int r = t >> 5;
    const int c = t & 31;

    float4 w1r[8];
    #pragma unroll
    for (int q = 0; q < 8; ++q)
        w1r[q] = *(const float4*)(W1 + c * DIM + q * 4);

    const int ntiles = (n_nodes + 7) >> 3;

    for (int tile = blockIdx.x; tile < ntiles; tile += gridDim.x) {
        const int row = tile * 8 + r;
        __syncthreads();
        if (row < n_nodes) xs[r][c] = x[(long)row * DIM + c];
        __syncthreads();
        if (row < n_nodes) {
            const float4* xr = (const float4*)xs[r];
            float a1 = 0.0f;
            #pragma unroll
            for (int q = 0; q < 8; ++q) {
                float4 xv = xr[q];
                a1 += xv.x * w1r[q].x + xv.y * w1r[q].y + xv.z * w1r[q].z + xv.w * w1r[q].w;
            }
            float hi = __shfl_down(a1, 1);
            if ((c & 1) == 0) {
                __hip_bfloat16 blo = __float2bfloat16(a1);
                __hip_bfloat16 bhi = __float2bfloat16(hi);
                unsigned pack = ((unsigned)(*(unsigned short*)&bhi) << 16)
                              | (unsigned)(*(unsigned short*)&blo);
                y32[(size_t)row * 16 + (c >> 1)] = pack;
            }
        }
    }
}

// ---------------------------------------------------------------------------
// Pass 1: bucket scatter (r13/r17 proven shape: 98 fat blocks, rank merged
// into histogram atomic).
// ---------------------------------------------------------------------------
__global__ __launch_bounds__(1024) void bucket_scatter_kernel(
    const int* __restrict__ src, const int* __restrict__ dst,
    int* __restrict__ cursor, unsigned* __restrict__ bedges, int nE)
{
    __shared__ int cnt[NBINS];
    __shared__ int base[NBINS];

    const int t = threadIdx.x;
    const long blockStart = (long)blockIdx.x * EPB;

    for (int i = t; i < NBINS; i += 1024) cnt[i] = 0;
    __syncthreads();

    int es[EPT], ed[EPT], rk[EPT];
    #pragma unroll
    for (int i = 0; i < EPT; ++i) {
        long e = blockStart + (long)i * 1024 + t;
        if (e < nE) { es[i] = src[e]; ed[i] = dst[e]; }
        else        { es[i] = -1;     ed[i] = 0;      }
    }
    #pragma unroll
    for (int i = 0; i < EPT; ++i) {
        if (es[i] >= 0) rk[i] = atomicAdd(&cnt[ed[i] >> LOG_NPB], 1);
    }
    __syncthreads();

    for (int i = t; i < NBINS; i += 1024) {
        int c = cnt[i];
        if (c > 0) base[i] = atomicAdd(&cursor[i], c);
    }
    __syncthreads();

    #pragma unroll
    for (int i = 0; i < EPT; ++i) {
        if (es[i] >= 0) {
            int b = ed[i] >> LOG_NPB;
            int p = base[b] + rk[i];
            if (p < (b + 1) * CAP)
                bedges[p] = ((unsigned)es[i] << LOG_NPB) | (unsigned)(ed[i] & (NPB - 1));
        }
    }
}

// ---------------------------------------------------------------------------
// Pass 2 (fused): per-bucket LDS sort + pipelined gather + W2 skip-connection.
// Lane (slot,li) holds W2^T tile w2t[k'][j] = W2[4li+j][4slot+k'] in 16 regs;
// its matvec partials ride the existing shfl_xor slot-reduction. The x row is
// prefetched in the same pipeline slot that used to prefetch the out row.
// out written exactly once per node (no RMW).
// ---------------------------------------------------------------------------
__global__ __launch_bounds__(512) void sort_gather_kernel(
    const int* __restrict__ cursor, const unsigned* __restrict__ bedges,
    const unsigned short* __restrict__ yb,
    const float* __restrict__ x,
    const float* __restrict__ W2,
    const float* __restrict__ b2,
    float* __restrict__ out, int n_nodes)
{
    __shared__ unsigned ent[CAP];      // 16 KB raw entries
    __shared__ unsigned sorted[CAP];   // 16 KB src ids sorted by local dst
    __shared__ int cnt[NPB];
    __shared__ int ex[NPB];
    __shared__ int cur[NPB];

    const int b = blockIdx.x;
    const int t = threadIdx.x;
    const int wv   = t >> 6;      // wave 0..7
    const int lane = t & 63;
    const int slot = lane >> 3;   // 0..7: edge slot / k-quad
    const int li   = lane & 7;    // output dims li*4..li*4+3

    // per-lane W2^T tile + bias
    float w2t[4][4];
    #pragma unroll
    for (int j = 0; j < 4; ++j)
        #pragma unroll
        for (int k = 0; k < 4; ++k)
            w2t[k][j] = W2[(size_t)(4 * li + j) * DIM + 4 * slot + k];
    const float4 bias = ((const float4*)b2)[li];

    const int start = b * CAP;
    int n = cursor[b] - start;
    if (n > CAP) n = CAP;
    if (n < 0) n = 0;

    if (t < NPB) { cnt[t] = 0; cur[t] = 0; }
    __syncthreads();

    for (int i = t; i < n; i += 512) {
        unsigned e = bedges[start + i];
        ent[i] = e;
        atomicAdd(&cnt[e & (NPB - 1)], 1);
    }
    __syncthreads();

    // single-wave exclusive scan over 128 bins (2 bins/lane, no barriers)
    if (t < 64) {
        int c0 = cnt[2 * t];
        int c1 = cnt[2 * t + 1];
        int v  = c0 + c1;
        #pragma unroll
        for (int off = 1; off < 64; off <<= 1) {
            int u = __shfl_up(v, off);
            if (t >= off) v += u;
        }
        int pbase = v - (c0 + c1);
        ex[2 * t]     = pbase;
        ex[2 * t + 1] = pbase + c0;
    }
    __syncthreads();

    for (int i = t; i < n; i += 512) {
        unsigned e = ent[i];
        int bin = (int)(e & (NPB - 1));
        int r = atomicAdd(&cur[bin], 1);
        sorted[ex[bin] + r] = e >> LOG_NPB;
    }
    __syncthreads();

    // ---- pipelined gather + skip phase ----
    int ln   = wv;
    int node = b * NPB + ln;
    if (node >= n_nodes) return;

    int st = ex[ln];
    int d  = cnt[ln];
    int s[4];
    #pragma unroll
    for (int k = 0; k < 4; ++k) {
        int e = slot + 8 * k;
        int idx = (e < d) ? e : (d > 0 ? d - 1 : 0);
        s[k] = (int)sorted[(d > 0 ? st : 0) + idx];
    }
    float4 xv = ((const float4*)(x + ((size_t)node << 5)))[slot];

    while (true) {
        // issue current node's y loads (chunk k only if 8k < d, wave-uniform)
        ushort4 u[4];
        #pragma unroll
        for (int k = 0; k < 4; ++k) {
            if (8 * k < d)
                u[k] = *(const ushort4*)(yb + ((size_t)s[k] << 5) + (li << 2));
        }

        // prefetch next node's state while y loads are in flight
        const int ln_n   = ln + 8;
        const int node_n = node + 8;
        const bool have_n = (ln_n < NPB) && (node_n < n_nodes);
        int st_n = 0, d_n = 0;
        int sn[4];
        float4 xv_n = make_float4(0.f, 0.f, 0.f, 0.f);
        if (have_n) {
            st_n = ex[ln_n];
            d_n  = cnt[ln_n];
            #pragma unroll
            for (int k = 0; k < 4; ++k) {
                int e = slot + 8 * k;
                int idx = (e < d_n) ? e : (d_n > 0 ? d_n - 1 : 0);
                sn[k] = (int)sorted[(d_n > 0 ? st_n : 0) + idx];
            }
            xv_n = ((const float4*)(x + ((size_t)node_n << 5)))[slot];
        }

        // W2 matvec partials (k in [4slot,4slot+4)) — VALU under load shadow
        float a0, a1, a2, a3;
        a0 = xv.x * w2t[0][0] + xv.y * w2t[1][0] + xv.z * w2t[2][0] + xv.w * w2t[3][0];
        a1 = xv.x * w2t[0][1] + xv.y * w2t[1][1] + xv.z * w2t[2][1] + xv.w * w2t[3][1];
        a2 = xv.x * w2t[0][2] + xv.y * w2t[1][2] + xv.z * w2t[2][2] + xv.w * w2t[3][2];
        a3 = xv.x * w2t[0][3] + xv.y * w2t[1][3] + xv.z * w2t[2][3] + xv.w * w2t[3][3];

        // gather adds
        #pragma unroll
        for (int k = 0; k < 4; ++k) {
            if (8 * k < d) {
                const bool v = (slot + 8 * k) < d;
                a0 += v ? __uint_as_float((unsigned)u[k].x << 16) : 0.f;
                a1 += v ? __uint_as_float((unsigned)u[k].y << 16) : 0.f;
                a2 += v ? __uint_as_float((unsigned)u[k].z << 16) : 0.f;
                a3 += v ? __uint_as_float((unsigned)u[k].w << 16) : 0.f;
            }
        }
        // rare tail: degree > 32
        for (int e0 = 32 + slot; e0 < d; e0 += 8) {
            int ss = (int)sorted[st + e0];
            ushort4 uu = *(const ushort4*)(yb + ((size_t)ss << 5) + (li << 2));
            a0 += __uint_as_float((unsigned)uu.x << 16);
            a1 += __uint_as_float((unsigned)uu.y << 16);
            a2 += __uint_as_float((unsigned)uu.z << 16);
            a3 += __uint_as_float((unsigned)uu.w << 16);
        }

        #pragma unroll
        for (int m = 8; m < 64; m <<= 1) {
            a0 += __shfl_xor(a0, m);
            a1 += __shfl_xor(a1, m);
            a2 += __shfl_xor(a2, m);
            a3 += __shfl_xor(a3, m);
        }

        if (slot == 0) {
            float4 w;
            w.x = a0 + bias.x;
            w.y = a1 + bias.y;
            w.z = a2 + bias.z;
            w.w = a3 + bias.w;
            ((float4*)(out + ((size_t)node << 5)))[li] = w;   // single write, no RMW
        }

        if (!have_n) break;
        ln = ln_n; node = node_n; st = st_n; d = d_n;
        s[0] = sn[0]; s[1] = sn[1]; s[2] = sn[2]; s[3] = sn[3];
        xv = xv_n;
    }
}

extern "C" void kernel_launch(void* const* d_in, const int* in_sizes, int n_in,
                              void* d_out, int out_size, void* d_ws, size_t ws_size,
                              hipStream_t stream) {
    const float* x  = (const float*)d_in[0];
    const float* W1 = (const float*)d_in[1];
    const float* W2 = (const float*)d_in[2];
    const float* b2 = (const float*)d_in[3];
    const int*   ei = (const int*)d_in[4];

    const int n_nodes = in_sizes[0] / DIM;   // 100000
    const int n_edges = in_sizes[4] / 2;     // 1,600,000
    const int* src = ei;
    const int* dst = ei + n_edges;
    float* out = (float*)d_out;

    const int nb = (n_nodes + NPB - 1) / NPB;    // 782

    char* basep = (char*)d_ws;
    size_t off = 0;
    auto alloc = [&](size_t bytes) {
        char* p = basep + off;
        off = (off + bytes + 255) & ~(size_t)255;
        return p;
    };
    unsigned* y32    = (unsigned*)alloc((size_t)n_nodes * DIM * sizeof(unsigned short));
    int*      cursor = (int*)     alloc((size_t)nb * sizeof(int));
    unsigned* bedges = (unsigned*)alloc((size_t)nb * CAP * sizeof(unsigned));
    (void)ws_size;

    lin_y_kernel<<<1024, 256, 0, stream>>>(x, W1, y32, cursor, nb, n_nodes);
    bucket_scatter_kernel<<<(n_edges + EPB - 1) / EPB, 1024, 0, stream>>>(src, dst, cursor, bedges, n_edges);
    sort_gather_kernel<<<nb, 512, 0, stream>>>(cursor, bedges, (const unsigned short*)y32,
                                               x, W2, b2, out, n_nodes);
}